// Round 1
// baseline (163.477 us; speedup 1.0000x reference)
//
#include <hip/hip_runtime.h>
#include <hip/hip_bf16.h>
#include <stdint.h>

typedef __hip_bfloat16 bf16_t;
typedef __attribute__((ext_vector_type(8))) __bf16 bf16x8;
typedef __attribute__((ext_vector_type(4))) float floatx4;

#define BK 64

// async 16B global->LDS (wave-uniform LDS base + lane*16; our layouts satisfy this)
__device__ inline void async_load16(const void* g, void* l) {
  __builtin_amdgcn_global_load_lds(
      (const __attribute__((address_space(1))) unsigned int*)g,
      (__attribute__((address_space(3))) unsigned int*)l,
      16, 0, 0);
}

__device__ inline unsigned short bf16_bits(float f) {
  bf16_t b = __float2bfloat16(f);
  return *(const unsigned short*)&b;
}

// fp32 -> bf16 for all 5 tensors + S zero-init, one launch.
__global__ void cvt_all(const float* __restrict__ h, const float* __restrict__ Wq,
                        const float* __restrict__ Wk, const float* __restrict__ Wv,
                        const float* __restrict__ Wo,
                        bf16_t* __restrict__ hb, bf16_t* __restrict__ Wqb,
                        bf16_t* __restrict__ Wkb, bf16_t* __restrict__ Wvb,
                        bf16_t* __restrict__ Wob, float* __restrict__ S)
{
  const int bid = blockIdx.x;
  if (bid >= 8192) {
    float4* s4 = (float4*)S;      // 131072 floats = 32768 float4
    const int base = (bid - 8192) * 256 + threadIdx.x;   // 0..511
#pragma unroll
    for (int i = 0; i < 64; ++i)
      s4[base + i * 512] = (float4){0.f, 0.f, 0.f, 0.f};
    return;
  }
  const float* s; bf16_t* d; int base;
  if (bid < 4096)      { s = h;  d = hb;  base = bid; }
  else if (bid < 5120) { s = Wq; d = Wqb; base = bid - 4096; }
  else if (bid < 6144) { s = Wk; d = Wkb; base = bid - 5120; }
  else if (bid < 7168) { s = Wv; d = Wvb; base = bid - 6144; }
  else                 { s = Wo; d = Wob; base = bid - 7168; }
  const int i = (base * 256 + threadIdx.x) * 4;
  float4 f = *(const float4*)(s + i);
  union { unsigned short u[4]; uint2 v; } p;
  p.u[0] = bf16_bits(f.x); p.u[1] = bf16_bits(f.y);
  p.u[2] = bf16_bits(f.z); p.u[3] = bf16_bits(f.w);
  *(uint2*)(d + i) = p.v;
}

// ---------------------------------------------------------------------------
// QKV GEMM, 8-phase-style ring schedule (T2+T3+T4+T5).
// C[M,N] = A[M,K] * B[N,K]^T ; bf16; fp32 accum; 16x16x32 MFMA.
// Tile 256x256, BKh=32 (K-half granularity), 512 threads = 8 waves (2M x 4N),
// per-wave output 128x64 (8x4 fragments). LDS = 4-slot ring of K-halves per
// matrix: slot H&3 holds K-half H; 128 KiB total, 1 block/CU.
// Per phase H: vmcnt(8) [half H landed, 3 halves in flight] -> barrier ->
// issue 4 global_load_lds for half H+3 (into slot (H+3)&3, whose readers
// finished before THIS barrier) -> 12 ds_read_b128 -> 32 MFMA (setprio).
// lgkmcnt(0)+sched_barrier at phase end pins reads before next barrier.
// LDS swizzle: within a 64B row (4 granules of 16B), granule g of row r at
// slot g^(r&3); inverse applied to the global source address so the
// global_load_lds destination stays lane-linear (guideline 21).
// mat0 -> Qbuf row-major; mat1/mat2 -> Kt/Vt TRANSPOSED [bh][64][2048 m].
// ---------------------------------------------------------------------------
__global__ __launch_bounds__(512, 2)
void gemm_qkv(const bf16_t* __restrict__ A,
              const bf16_t* __restrict__ B0, const bf16_t* __restrict__ B1,
              const bf16_t* __restrict__ B2,
              bf16_t* __restrict__ Qbuf,
              bf16_t* __restrict__ Kt, bf16_t* __restrict__ Vt)
{
  __shared__ alignas(16) __bf16 Asm[4 * 256 * 32];   // 64 KiB: ring slots 0..3
  __shared__ alignas(16) __bf16 Bsm[4 * 256 * 32];   // 64 KiB

  const int t = threadIdx.x;
  const int lane = t & 63;
  const int wave = t >> 6;       // 0..7
  const int wm = wave >> 2;      // 0..1 -> 128-row strip
  const int wn = wave & 3;       // 0..3 -> 64-col strip

  const int m0 = blockIdx.x * 256;
  const int nblk = blockIdx.y * 256;
  const int mat = nblk >> 10;
  const bf16_t* __restrict__ B = (mat == 0) ? B0 : ((mat == 1) ? B1 : B2);
  const int n0 = nblk & 1023;

  // ---- staging addressing: 16 chunks of 1KB (16 rows x 64B); wave w owns
  // chunks 2w, 2w+1. lane ln: row = chunk*16 + (ln>>2), LDS slot = ln&3,
  // global granule = (ln&3) ^ (row&3).
  const int ln2 = lane >> 2;
  const int gsrc = (lane & 3) ^ (ln2 & 3);
  const int c0 = wave * 2;
  const int row0 = c0 * 16 + ln2;
  const bf16_t* __restrict__ srcA0 = A + (size_t)(m0 + row0) * 1024 + gsrc * 8;
  const bf16_t* __restrict__ srcA1 = srcA0 + (size_t)16 * 1024;
  const bf16_t* __restrict__ srcB0 = B + (size_t)(n0 + row0) * 1024 + gsrc * 8;
  const bf16_t* __restrict__ srcB1 = srcB0 + (size_t)16 * 1024;
  __bf16* dstA0 = &Asm[c0 * 512 + lane * 8];
  __bf16* dstA1 = dstA0 + 512;
  __bf16* dstB0 = &Bsm[c0 * 512 + lane * 8];
  __bf16* dstB1 = dstB0 + 512;

#define STAGE(HS) do {                                          \
    const int reg_ = ((HS) & 3) * 8192;                         \
    const int koff_ = (HS) * 32;                                \
    async_load16(srcA0 + koff_, dstA0 + reg_);                  \
    async_load16(srcA1 + koff_, dstA1 + reg_);                  \
    async_load16(srcB0 + koff_, dstB0 + reg_);                  \
    async_load16(srcB1 + koff_, dstB1 + reg_);                  \
  } while (0)

  // ---- read addressing: frag row r -> r&3 == lane&3; granule = lane>>4.
  const int slotr = (lane >> 4) ^ (lane & 3);
  const int aoff0 = (wm * 128 + (lane & 15)) * 32 + slotr * 8;
  const int boff0 = (wn * 64 + (lane & 15)) * 32 + slotr * 8;

  floatx4 acc[8][4];
#pragma unroll
  for (int i = 0; i < 8; ++i)
#pragma unroll
    for (int j = 0; j < 4; ++j)
      acc[i][j] = (floatx4){0.f, 0.f, 0.f, 0.f};

#define COMPUTE(H_) do {                                                      \
    const int reg_ = ((H_) & 3) * 8192;                                       \
    bf16x8 af[8], bv[4];                                                      \
    _Pragma("unroll")                                                         \
    for (int i = 0; i < 8; ++i)                                               \
      af[i] = *(const bf16x8*)&Asm[reg_ + aoff0 + i * 512];                   \
    _Pragma("unroll")                                                         \
    for (int j = 0; j < 4; ++j)                                               \
      bv[j] = *(const bf16x8*)&Bsm[reg_ + boff0 + j * 512];                   \
    __builtin_amdgcn_s_setprio(1);                                            \
    _Pragma("unroll")                                                         \
    for (int i = 0; i < 8; ++i)                                               \
      _Pragma("unroll")                                                       \
      for (int j = 0; j < 4; ++j)                                             \
        acc[i][j] = __builtin_amdgcn_mfma_f32_16x16x32_bf16(                  \
            af[i], bv[j], acc[i][j], 0, 0, 0);                                \
    __builtin_amdgcn_s_setprio(0);                                            \
  } while (0)

#define PHASE(H_, VMSTR, DO_ISSUE) do {                                       \
    asm volatile("s_waitcnt " VMSTR ::: "memory");                            \
    __builtin_amdgcn_s_barrier();                                             \
    __builtin_amdgcn_sched_barrier(0);                                        \
    if (DO_ISSUE) STAGE((H_) + 3);                                            \
    COMPUTE(H_);                                                              \
    asm volatile("s_waitcnt lgkmcnt(0)" ::: "memory");                        \
    __builtin_amdgcn_sched_barrier(0);                                        \
  } while (0)

  // prologue: 3 K-halves in flight (12 loads/thread)
  STAGE(0); STAGE(1); STAGE(2);

  // 32 K-halves total (K=1024). Phases 0..28 issue half H+3.
#pragma unroll 1
  for (int h = 0; h < 29; ++h) {
    PHASE(h, "vmcnt(8)", true);
  }
  PHASE(29, "vmcnt(8)", false);
  PHASE(30, "vmcnt(4)", false);
  PHASE(31, "vmcnt(0)", false);

#undef PHASE
#undef COMPUTE
#undef STAGE

  const int ccol = lane & 15;
  const int crow = (lane >> 4) * 4;

  if (mat != 0) {
    bf16_t* __restrict__ T = (mat == 1) ? Kt : Vt;
#pragma unroll
    for (int i = 0; i < 8; ++i) {
      const int grow = m0 + wm * 128 + i * 16 + crow;   // global row (incl b)
      const int bidx = grow >> 11, mloc = grow & 2047;
#pragma unroll
      for (int j = 0; j < 4; ++j) {
        const int lc = n0 + wn * 64 + j * 16 + ccol;    // 0..1023
        const int hidx = lc >> 6, d = lc & 63;
        union { unsigned short u[4]; uint2 v; } p;
#pragma unroll
        for (int r = 0; r < 4; ++r) p.u[r] = bf16_bits(acc[i][j][r]);
        *(uint2*)(T + (((size_t)bidx * 16 + hidx) * 64 + d) * 2048 + mloc) = p.v;
      }
    }
    return;
  }

#pragma unroll
  for (int i = 0; i < 8; ++i) {
#pragma unroll
    for (int j = 0; j < 4; ++j) {
      const int gcol = n0 + wn * 64 + j * 16 + ccol;
      const int grow = m0 + wm * 128 + i * 16 + crow;
#pragma unroll
      for (int r = 0; r < 4; ++r)
        Qbuf[(size_t)(grow + r) * 1024 + gcol] = __float2bfloat16(acc[i][j][r]);
    }
  }
}

// S[bh][d][e] += sum_m Kt[bh][d][m] * Vt[bh][e][m]  -- NT MFMA GEMM (16x16x32).
// grid (32 bh, 8 ksplit); fp32 atomic epilogue (tiny, L2-resident).
__global__ __launch_bounds__(256, 2)
void ktv_gemm(const bf16_t* __restrict__ Kt, const bf16_t* __restrict__ Vt,
              float* __restrict__ S)
{
  __shared__ alignas(16) __bf16 As[64 * 64];   // Kt tile (d rows)
  __shared__ alignas(16) __bf16 Bs[64 * 64];   // Vt tile (e rows)

  const int t = threadIdx.x;
  const int lane = t & 63;
  const int wave = t >> 6;            // d-strip = wave*16
  const int bh = blockIdx.x;
  const int kc = blockIdx.y;          // k-range kc*256 .. +256

  const bf16_t* A = Kt + (size_t)bh * 64 * 2048;
  const bf16_t* B = Vt + (size_t)bh * 64 * 2048;

  floatx4 acc[4];
#pragma unroll
  for (int j = 0; j < 4; ++j) acc[j] = (floatx4){0.f, 0.f, 0.f, 0.f};

  const int srow = t >> 3;   // 0..31
  const int sgs = t & 7;

  for (int k0 = kc * 256; k0 < kc * 256 + 256; k0 += 64) {
#pragma unroll
    for (int r2 = 0; r2 < 2; ++r2) {
      const int row = r2 * 32 + srow;
      const int gsrc = sgs ^ (row & 7);
      async_load16(A + (size_t)row * 2048 + k0 + gsrc * 8, &As[row * 64 + sgs * 8]);
      async_load16(B + (size_t)row * 2048 + k0 + gsrc * 8, &Bs[row * 64 + sgs * 8]);
    }
    __syncthreads();
#pragma unroll
    for (int ks = 0; ks < 2; ++ks) {
      bf16x8 af, bfv[4];
      {
        const int row = wave * 16 + (lane & 15);
        const int g = ks * 4 + (lane >> 4);
        af = *(const bf16x8*)&As[row * 64 + (g ^ (row & 7)) * 8];
      }
#pragma unroll
      for (int j = 0; j < 4; ++j) {
        const int row = j * 16 + (lane & 15);
        const int g = ks * 4 + (lane >> 4);
        bfv[j] = *(const bf16x8*)&Bs[row * 64 + (g ^ (row & 7)) * 8];
      }
#pragma unroll
      for (int j = 0; j < 4; ++j)
        acc[j] = __builtin_amdgcn_mfma_f32_16x16x32_bf16(af, bfv[j], acc[j], 0, 0, 0);
    }
    __syncthreads();
  }

  // C[d][e]: d = wave*16 + crow + r, e = j*16 + ccol
  const int ccol = lane & 15;
  const int crow = (lane >> 4) * 4;
  float* Sp = S + (size_t)bh * 4096;
#pragma unroll
  for (int j = 0; j < 4; ++j)
#pragma unroll
    for (int r = 0; r < 4; ++r)
      unsafeAtomicAdd(&Sp[(wave * 16 + crow + r) * 64 + j * 16 + ccol], acc[j][r]);
}

// W_effT[b][n][h*64+d] = sum_e Wo[n][h*64+e] * S[bh][d][e]   (16x16x32 MFMA)
__global__ __launch_bounds__(256, 2)
void weff_mfma(const bf16_t* __restrict__ Wob, const float* __restrict__ S,
               bf16_t* __restrict__ WeffT)
{
  __shared__ alignas(16) __bf16 Aw[128 * 64];
  __shared__ alignas(16) __bf16 Sb[64 * 64];

  const int t = threadIdx.x;
  const int lane = t & 63;
  const int wave = t >> 6;          // 0..3 -> 32-row n strip
  const int bh = blockIdx.x;
  const int b = bh >> 4, hh = bh & 15;
  const int nt = blockIdx.y;        // 0..7 -> 128 n rows

  const bf16_t* wbase = Wob + (size_t)(nt * 128) * 1024 + hh * 64;
  const int srow = t >> 3;          // 0..31
  const int sgs = t & 7;
#pragma unroll
  for (int r4 = 0; r4 < 4; ++r4) {
    const int row = r4 * 32 + srow;
    const int gsrc = sgs ^ (row & 7);
    async_load16(wbase + (size_t)row * 1024 + gsrc * 8, &Aw[row * 64 + sgs * 8]);
  }
  // stage S (fp32 -> bf16), XOR-swizzled; rows = d, cols = e
  {
    const int r = t >> 2;           // 0..63 (d row)
    const int g0 = (t & 3) * 2;
    const float* sp = S + (size_t)bh * 4096 + r * 64;
#pragma unroll
    for (int gg = 0; gg < 2; ++gg) {
      const int g = g0 + gg;
      const int gs = g ^ (r & 7);
      const float4 f0 = *(const float4*)(sp + gs * 8);
      const float4 f1 = *(const float4*)(sp + gs * 8 + 4);
      union { unsigned short u[8]; uint4 v; } pk;
      pk.u[0] = bf16_bits(f0.x); pk.u[1] = bf16_bits(f0.y);
      pk.u[2] = bf16_bits(f0.z); pk.u[3] = bf16_bits(f0.w);
      pk.u[4] = bf16_bits(f1.x); pk.u[5] = bf16_bits(f1.y);
      pk.u[6] = bf16_bits(f1.z); pk.u[7] = bf16_bits(f1.w);
      *(uint4*)&Sb[r * 64 + g * 8] = pk.v;
    }
  }
  __syncthreads();

  floatx4 acc[2][4];
#pragma unroll
  for (int i = 0; i < 2; ++i)
#pragma unroll
    for (int j = 0; j < 4; ++j)
      acc[i][j] = (floatx4){0.f, 0.f, 0.f, 0.f};

#pragma unroll
  for (int ks = 0; ks < 2; ++ks) {
    bf16x8 af[2], bfv[4];
#pragma unroll
    for (int i = 0; i < 2; ++i) {
      const int row = wave * 32 + i * 16 + (lane & 15);
      const int g = ks * 4 + (lane >> 4);
      af[i] = *(const bf16x8*)&Aw[row * 64 + (g ^ (row & 7)) * 8];
    }
#pragma unroll
    for (int j = 0; j < 4; ++j) {
      const int row = j * 16 + (lane & 15);       // d
      const int g = ks * 4 + (lane >> 4);
      bfv[j] = *(const bf16x8*)&Sb[row * 64 + (g ^ (row & 7)) * 8];
    }
#pragma unroll
    for (int i = 0; i < 2; ++i)
#pragma unroll
      for (int j = 0; j < 4; ++j)
        acc[i][j] = __builtin_amdgcn_mfma_f32_16x16x32_bf16(
            af[i], bfv[j], acc[i][j], 0, 0, 0);
  }

  const int ccol = lane & 15;
  const int crow = (lane >> 4) * 4;
  bf16_t* Wt = WeffT + (size_t)b * 1024 * 1024;
#pragma unroll
  for (int i = 0; i < 2; ++i) {
#pragma unroll
    for (int j = 0; j < 4; ++j) {
      const int hd = hh * 64 + j * 16 + ccol;
      const int n = nt * 128 + wave * 32 + i * 16 + crow;
#pragma unroll
      for (int r = 0; r < 4; ++r)
        Wt[(size_t)(n + r) * 1024 + hd] = __float2bfloat16(acc[i][j][r]);
    }
  }
}

// out[m][n] = sum_hd Q[m][hd] * WeffT[b][n][hd]. 16x16x32 MFMA, direct fp32 stores.
// BM=64 x BN=128 tiles -> grid (64,8) = 512 blocks = 2 blocks/CU.
__global__ __launch_bounds__(256, 2)
void gemm_final(const bf16_t* __restrict__ Q, const bf16_t* __restrict__ WeffT,
                float* __restrict__ C)
{
  __shared__ alignas(16) __bf16 As[64 * BK];    // Q tile
  __shared__ alignas(16) __bf16 Bs[128 * BK];   // WeffT tile

  const int t = threadIdx.x;
  const int lane = t & 63;
  const int wave = t >> 6;
  const int wm = wave >> 1;   // 0..1 (32-row strips)
  const int wn = wave & 1;    // 0..1 (64-col strips)

  const int m0 = blockIdx.x * 64;
  const int n0 = blockIdx.y * 128;
  const bf16_t* __restrict__ B = WeffT + (size_t)(m0 >> 11) * 1024 * 1024;

  floatx4 acc[2][4];
#pragma unroll
  for (int i = 0; i < 2; ++i)
#pragma unroll
    for (int j = 0; j < 4; ++j)
      acc[i][j] = (floatx4){0.f, 0.f, 0.f, 0.f};

  const int srow = t >> 3;
  const int sgs = t & 7;

  for (int k0 = 0; k0 < 1024; k0 += BK) {
#pragma unroll
    for (int r2 = 0; r2 < 2; ++r2) {
      const int row = r2 * 32 + srow;
      const int gsrc = sgs ^ (row & 7);
      async_load16(Q + (size_t)(m0 + row) * 1024 + k0 + gsrc * 8,
                   &As[row * BK + sgs * 8]);
    }
#pragma unroll
    for (int r4 = 0; r4 < 4; ++r4) {
      const int row = r4 * 32 + srow;
      const int gsrc = sgs ^ (row & 7);
      async_load16(B + (size_t)(n0 + row) * 1024 + k0 + gsrc * 8,
                   &Bs[row * BK + sgs * 8]);
    }
    __syncthreads();
#pragma unroll
    for (int ks = 0; ks < 2; ++ks) {
      bf16x8 af[2], bfv[4];
#pragma unroll
      for (int i = 0; i < 2; ++i) {
        const int row = wm * 32 + i * 16 + (lane & 15);
        const int g = ks * 4 + (lane >> 4);
        af[i] = *(const bf16x8*)&As[row * BK + (g ^ (row & 7)) * 8];
      }
#pragma unroll
      for (int j = 0; j < 4; ++j) {
        const int row = wn * 64 + j * 16 + (lane & 15);
        const int g = ks * 4 + (lane >> 4);
        bfv[j] = *(const bf16x8*)&Bs[row * BK + (g ^ (row & 7)) * 8];
      }
#pragma unroll
      for (int i = 0; i < 2; ++i)
#pragma unroll
        for (int j = 0; j < 4; ++j)
          acc[i][j] = __builtin_amdgcn_mfma_f32_16x16x32_bf16(
              af[i], bfv[j], acc[i][j], 0, 0, 0);
    }
    __syncthreads();
  }

  const int ccol = lane & 15;
  const int crow = (lane >> 4) * 4;
#pragma unroll
  for (int i = 0; i < 2; ++i) {
#pragma unroll
    for (int j = 0; j < 4; ++j) {
      const int gcol = n0 + wn * 64 + j * 16 + ccol;
      const int grow = m0 + wm * 32 + i * 16 + crow;
#pragma unroll
      for (int r = 0; r < 4; ++r)
        C[(size_t)(grow + r) * 1024 + gcol] = acc[i][j][r];
    }
  }
}

extern "C" void kernel_launch(void* const* d_in, const int* in_sizes, int n_in,
                              void* d_out, int out_size, void* d_ws, size_t ws_size,
                              hipStream_t stream)
{
  const float* h  = (const float*)d_in[0];
  const float* Wq = (const float*)d_in[1];
  const float* Wk = (const float*)d_in[2];
  const float* Wv = (const float*)d_in[3];
  // d_in[4] = Wspan: dead code in reference
  const float* Wo = (const float*)d_in[5];
  float* out = (float*)d_out;

  char* ws = (char*)d_ws;
  bf16_t* hb    = (bf16_t*)(ws);                 // [4096,1024] bf16, 8 MB (dead after QKV)
  bf16_t* WeffT = (bf16_t*)(ws);                 // [2][1024,1024] bf16, 4 MB (reuses hb)
  bf16_t* Wqb   = (bf16_t*)(ws + (8u << 20));    // 2 MB each
  bf16_t* Wkb   = (bf16_t*)(ws + (10u << 20));
  bf16_t* Wvb   = (bf16_t*)(ws + (12u << 20));
  bf16_t* Wob   = (bf16_t*)(ws + (14u << 20));
  bf16_t* Qbuf  = (bf16_t*)(ws + (16u << 20));   // [4096,1024] bf16, 8 MB
  bf16_t* Kt    = (bf16_t*)(ws + (24u << 20));   // [32][64][2048] bf16, 8 MB
  bf16_t* Vt    = (bf16_t*)(ws + (32u << 20));   // [32][64][2048] bf16, 8 MB
  float*  S     = (float*) (ws + (40u << 20));   // [32][64][64] fp32, d-major

  // conversions + S zero (one launch)
  cvt_all<<<dim3(8194), 256, 0, stream>>>(h, Wq, Wk, Wv, Wo, hb, Wqb, Wkb, Wvb, Wob, S);

  // Q -> Qbuf; K,V -> Kt,Vt (transposed, m-contiguous). 256x256 tiles, 8-phase ring.
  gemm_qkv<<<dim3(16, 12), 512, 0, stream>>>(hb, Wqb, Wkb, Wvb, Qbuf, Kt, Vt);
  // S[bh][d][e] = sum_m K*V (MFMA NT, split-K=8, atomic fp32 on tiny S)
  ktv_gemm<<<dim3(32, 8), 256, 0, stream>>>(Kt, Vt, S);
  // W_effT[b][n][hd] = sum_e Wo[n][he] * S[bh][d][e]  (overwrites dead hb)
  weff_mfma<<<dim3(32, 8), 256, 0, stream>>>(Wob, S, WeffT);
  // out = Q @ W_effT^T, direct fp32 stores, 2 blocks/CU
  gemm_final<<<dim3(64, 8), 256, 0, stream>>>(Qbuf, WeffT, out);
}

// Round 2
// 160.839 us; speedup vs baseline: 1.0164x; 1.0164x over previous
//
#include <hip/hip_runtime.h>
#include <hip/hip_bf16.h>
#include <stdint.h>

typedef __hip_bfloat16 bf16_t;
typedef __attribute__((ext_vector_type(8))) __bf16 bf16x8;
typedef __attribute__((ext_vector_type(4))) float floatx4;

#define BK 64

// async 16B global->LDS (wave-uniform LDS base + lane*16; our layouts satisfy this)
__device__ inline void async_load16(const void* g, void* l) {
  __builtin_amdgcn_global_load_lds(
      (const __attribute__((address_space(1))) unsigned int*)g,
      (__attribute__((address_space(3))) unsigned int*)l,
      16, 0, 0);
}

__device__ inline unsigned short bf16_bits(float f) {
  bf16_t b = __float2bfloat16(f);
  return *(const unsigned short*)&b;
}

// fp32 -> bf16 for all 5 tensors + S zero-init, one launch.
__global__ void cvt_all(const float* __restrict__ h, const float* __restrict__ Wq,
                        const float* __restrict__ Wk, const float* __restrict__ Wv,
                        const float* __restrict__ Wo,
                        bf16_t* __restrict__ hb, bf16_t* __restrict__ Wqb,
                        bf16_t* __restrict__ Wkb, bf16_t* __restrict__ Wvb,
                        bf16_t* __restrict__ Wob, float* __restrict__ S)
{
  const int bid = blockIdx.x;
  if (bid >= 8192) {
    float4* s4 = (float4*)S;      // 131072 floats = 32768 float4
    const int base = (bid - 8192) * 256 + threadIdx.x;   // 0..511
#pragma unroll
    for (int i = 0; i < 64; ++i)
      s4[base + i * 512] = (float4){0.f, 0.f, 0.f, 0.f};
    return;
  }
  const float* s; bf16_t* d; int base;
  if (bid < 4096)      { s = h;  d = hb;  base = bid; }
  else if (bid < 5120) { s = Wq; d = Wqb; base = bid - 4096; }
  else if (bid < 6144) { s = Wk; d = Wkb; base = bid - 5120; }
  else if (bid < 7168) { s = Wv; d = Wvb; base = bid - 6144; }
  else                 { s = Wo; d = Wob; base = bid - 7168; }
  const int i = (base * 256 + threadIdx.x) * 4;
  float4 f = *(const float4*)(s + i);
  union { unsigned short u[4]; uint2 v; } p;
  p.u[0] = bf16_bits(f.x); p.u[1] = bf16_bits(f.y);
  p.u[2] = bf16_bits(f.z); p.u[3] = bf16_bits(f.w);
  *(uint2*)(d + i) = p.v;
}

// ---------------------------------------------------------------------------
// QKV GEMM, ring schedule (T2+T3+T4+T5).
// C[M,N] = A[M,K] * B[N,K]^T ; bf16; fp32 accum; 16x16x32 MFMA.
// Tile 256x256, BKh=32 (K-half granularity), 512 threads = 8 waves (2M x 4N),
// per-wave output 128x64 (8x4 fragments). LDS = 4-slot ring of K-halves per
// matrix: slot H&3 holds K-half H; 128 KiB total, 1 block/CU.
// Per phase H: vmcnt(8) [half H landed, 3 halves in flight] -> barrier ->
// issue 4 global_load_lds for half H+3 (into slot (H+3)&3, whose readers
// finished before THIS barrier per trailing lgkmcnt(0)) -> 12 ds_read_b128
// (B first for earlier MFMA start) -> 32 MFMA (setprio).
// LDS swizzle (R2 fix): rows are 64B = 4 granules of 16B; 4-bank group of
// (row r, slot s) is (4r+s) mod 8, so the swizzle must mix r>>1 (not r&3):
//   s_phys = g ^ ((r>>1)&3)
// -> each group gets exactly 2 lanes per 16-lane quarter (2-way = free).
// Inverse applied to the global source so global_load_lds dest stays linear.
// mat0 -> Qbuf row-major; mat1/mat2 -> Kt/Vt TRANSPOSED [bh][64][2048 m].
// ---------------------------------------------------------------------------
__global__ __launch_bounds__(512, 2)
void gemm_qkv(const bf16_t* __restrict__ A,
              const bf16_t* __restrict__ B0, const bf16_t* __restrict__ B1,
              const bf16_t* __restrict__ B2,
              bf16_t* __restrict__ Qbuf,
              bf16_t* __restrict__ Kt, bf16_t* __restrict__ Vt)
{
  __shared__ alignas(16) __bf16 Asm[4 * 256 * 32];   // 64 KiB: ring slots 0..3
  __shared__ alignas(16) __bf16 Bsm[4 * 256 * 32];   // 64 KiB

  const int t = threadIdx.x;
  const int lane = t & 63;
  const int wave = t >> 6;       // 0..7
  const int wm = wave >> 2;      // 0..1 -> 128-row strip
  const int wn = wave & 3;       // 0..3 -> 64-col strip

  const int m0 = blockIdx.x * 256;
  const int nblk = blockIdx.y * 256;
  const int mat = nblk >> 10;
  const bf16_t* __restrict__ B = (mat == 0) ? B0 : ((mat == 1) ? B1 : B2);
  const int n0 = nblk & 1023;

  // ---- staging addressing: 16 chunks of 1KB (16 rows x 64B); wave w owns
  // chunks 2w, 2w+1. lane ln: row = chunk*16 + (ln>>2), LDS phys slot = ln&3,
  // global granule = (ln&3) ^ ((row>>1)&3) = (ln&3) ^ ((ln>>3)&3).
  const int ln2 = lane >> 2;
  const int gsrc = (lane & 3) ^ ((lane >> 3) & 3);
  const int c0 = wave * 2;
  const int row0 = c0 * 16 + ln2;
  const bf16_t* __restrict__ srcA0 = A + (size_t)(m0 + row0) * 1024 + gsrc * 8;
  const bf16_t* __restrict__ srcA1 = srcA0 + (size_t)16 * 1024;
  const bf16_t* __restrict__ srcB0 = B + (size_t)(n0 + row0) * 1024 + gsrc * 8;
  const bf16_t* __restrict__ srcB1 = srcB0 + (size_t)16 * 1024;
  __bf16* dstA0 = &Asm[c0 * 512 + lane * 8];
  __bf16* dstA1 = dstA0 + 512;
  __bf16* dstB0 = &Bsm[c0 * 512 + lane * 8];
  __bf16* dstB1 = dstB0 + 512;

#define STAGE(HS) do {                                          \
    const int reg_ = ((HS) & 3) * 8192;                         \
    const int koff_ = (HS) * 32;                                \
    async_load16(srcA0 + koff_, dstA0 + reg_);                  \
    async_load16(srcA1 + koff_, dstA1 + reg_);                  \
    async_load16(srcB0 + koff_, dstB0 + reg_);                  \
    async_load16(srcB1 + koff_, dstB1 + reg_);                  \
  } while (0)

  // ---- read addressing: frag row r = base + (lane&15), k-granule g = lane>>4.
  // phys slot = g ^ ((r>>1)&3); bases are ==0 mod 4 after >>1, so lane-only:
  const int slotr = (lane >> 4) ^ ((lane >> 1) & 3);
  const int aoff0 = (wm * 128 + (lane & 15)) * 32 + slotr * 8;
  const int boff0 = (wn * 64 + (lane & 15)) * 32 + slotr * 8;

  floatx4 acc[8][4];
#pragma unroll
  for (int i = 0; i < 8; ++i)
#pragma unroll
    for (int j = 0; j < 4; ++j)
      acc[i][j] = (floatx4){0.f, 0.f, 0.f, 0.f};

#define COMPUTE(H_) do {                                                      \
    const int reg_ = ((H_) & 3) * 8192;                                       \
    bf16x8 af[8], bv[4];                                                      \
    _Pragma("unroll")                                                         \
    for (int j = 0; j < 4; ++j)                                               \
      bv[j] = *(const bf16x8*)&Bsm[reg_ + boff0 + j * 512];                   \
    _Pragma("unroll")                                                         \
    for (int i = 0; i < 8; ++i)                                               \
      af[i] = *(const bf16x8*)&Asm[reg_ + aoff0 + i * 512];                   \
    __builtin_amdgcn_s_setprio(1);                                            \
    _Pragma("unroll")                                                         \
    for (int i = 0; i < 8; ++i)                                               \
      _Pragma("unroll")                                                       \
      for (int j = 0; j < 4; ++j)                                             \
        acc[i][j] = __builtin_amdgcn_mfma_f32_16x16x32_bf16(                  \
            af[i], bv[j], acc[i][j], 0, 0, 0);                                \
    __builtin_amdgcn_s_setprio(0);                                            \
  } while (0)

#define PHASE(H_, VMSTR, DO_ISSUE) do {                                       \
    asm volatile("s_waitcnt " VMSTR ::: "memory");                            \
    __builtin_amdgcn_s_barrier();                                             \
    __builtin_amdgcn_sched_barrier(0);                                        \
    if (DO_ISSUE) STAGE((H_) + 3);                                            \
    COMPUTE(H_);                                                              \
    asm volatile("s_waitcnt lgkmcnt(0)" ::: "memory");                        \
    __builtin_amdgcn_sched_barrier(0);                                        \
  } while (0)

  // prologue: 3 K-halves in flight (12 loads/thread)
  STAGE(0); STAGE(1); STAGE(2);

  // 32 K-halves total (K=1024). Phases 0..28 issue half H+3.
#pragma unroll 1
  for (int h = 0; h < 29; ++h) {
    PHASE(h, "vmcnt(8)", true);
  }
  PHASE(29, "vmcnt(8)", false);
  PHASE(30, "vmcnt(4)", false);
  PHASE(31, "vmcnt(0)", false);

#undef PHASE
#undef COMPUTE
#undef STAGE

  const int ccol = lane & 15;
  const int crow = (lane >> 4) * 4;

  if (mat != 0) {
    bf16_t* __restrict__ T = (mat == 1) ? Kt : Vt;
#pragma unroll
    for (int i = 0; i < 8; ++i) {
      const int grow = m0 + wm * 128 + i * 16 + crow;   // global row (incl b)
      const int bidx = grow >> 11, mloc = grow & 2047;
#pragma unroll
      for (int j = 0; j < 4; ++j) {
        const int lc = n0 + wn * 64 + j * 16 + ccol;    // 0..1023
        const int hidx = lc >> 6, d = lc & 63;
        union { unsigned short u[4]; uint2 v; } p;
#pragma unroll
        for (int r = 0; r < 4; ++r) p.u[r] = bf16_bits(acc[i][j][r]);
        *(uint2*)(T + (((size_t)bidx * 16 + hidx) * 64 + d) * 2048 + mloc) = p.v;
      }
    }
    return;
  }

#pragma unroll
  for (int i = 0; i < 8; ++i) {
#pragma unroll
    for (int j = 0; j < 4; ++j) {
      const int gcol = n0 + wn * 64 + j * 16 + ccol;
      const int grow = m0 + wm * 128 + i * 16 + crow;
#pragma unroll
      for (int r = 0; r < 4; ++r)
        Qbuf[(size_t)(grow + r) * 1024 + gcol] = __float2bfloat16(acc[i][j][r]);
    }
  }
}

// S[bh][d][e] += sum_m Kt[bh][d][m] * Vt[bh][e][m]  -- NT MFMA GEMM (16x16x32).
// grid (32 bh, 8 ksplit); fp32 atomic epilogue (tiny, L2-resident).
__global__ __launch_bounds__(256, 2)
void ktv_gemm(const bf16_t* __restrict__ Kt, const bf16_t* __restrict__ Vt,
              float* __restrict__ S)
{
  __shared__ alignas(16) __bf16 As[64 * 64];   // Kt tile (d rows)
  __shared__ alignas(16) __bf16 Bs[64 * 64];   // Vt tile (e rows)

  const int t = threadIdx.x;
  const int lane = t & 63;
  const int wave = t >> 6;            // d-strip = wave*16
  const int bh = blockIdx.x;
  const int kc = blockIdx.y;          // k-range kc*256 .. +256

  const bf16_t* A = Kt + (size_t)bh * 64 * 2048;
  const bf16_t* B = Vt + (size_t)bh * 64 * 2048;

  floatx4 acc[4];
#pragma unroll
  for (int j = 0; j < 4; ++j) acc[j] = (floatx4){0.f, 0.f, 0.f, 0.f};

  const int srow = t >> 3;   // 0..31
  const int sgs = t & 7;

  for (int k0 = kc * 256; k0 < kc * 256 + 256; k0 += 64) {
#pragma unroll
    for (int r2 = 0; r2 < 2; ++r2) {
      const int row = r2 * 32 + srow;
      const int gsrc = sgs ^ (row & 7);
      async_load16(A + (size_t)row * 2048 + k0 + gsrc * 8, &As[row * 64 + sgs * 8]);
      async_load16(B + (size_t)row * 2048 + k0 + gsrc * 8, &Bs[row * 64 + sgs * 8]);
    }
    __syncthreads();
#pragma unroll
    for (int ks = 0; ks < 2; ++ks) {
      bf16x8 af, bfv[4];
      {
        const int row = wave * 16 + (lane & 15);
        const int g = ks * 4 + (lane >> 4);
        af = *(const bf16x8*)&As[row * 64 + (g ^ (row & 7)) * 8];
      }
#pragma unroll
      for (int j = 0; j < 4; ++j) {
        const int row = j * 16 + (lane & 15);
        const int g = ks * 4 + (lane >> 4);
        bfv[j] = *(const bf16x8*)&Bs[row * 64 + (g ^ (row & 7)) * 8];
      }
#pragma unroll
      for (int j = 0; j < 4; ++j)
        acc[j] = __builtin_amdgcn_mfma_f32_16x16x32_bf16(af, bfv[j], acc[j], 0, 0, 0);
    }
    __syncthreads();
  }

  // C[d][e]: d = wave*16 + crow + r, e = j*16 + ccol
  const int ccol = lane & 15;
  const int crow = (lane >> 4) * 4;
  float* Sp = S + (size_t)bh * 4096;
#pragma unroll
  for (int j = 0; j < 4; ++j)
#pragma unroll
    for (int r = 0; r < 4; ++r)
      unsafeAtomicAdd(&Sp[(wave * 16 + crow + r) * 64 + j * 16 + ccol], acc[j][r]);
}

// W_effT[b][n][h*64+d] = sum_e Wo[n][h*64+e] * S[bh][d][e]   (16x16x32 MFMA)
__global__ __launch_bounds__(256, 2)
void weff_mfma(const bf16_t* __restrict__ Wob, const float* __restrict__ S,
               bf16_t* __restrict__ WeffT)
{
  __shared__ alignas(16) __bf16 Aw[128 * 64];
  __shared__ alignas(16) __bf16 Sb[64 * 64];

  const int t = threadIdx.x;
  const int lane = t & 63;
  const int wave = t >> 6;          // 0..3 -> 32-row n strip
  const int bh = blockIdx.x;
  const int b = bh >> 4, hh = bh & 15;
  const int nt = blockIdx.y;        // 0..7 -> 128 n rows

  const bf16_t* wbase = Wob + (size_t)(nt * 128) * 1024 + hh * 64;
  const int srow = t >> 3;          // 0..31
  const int sgs = t & 7;
#pragma unroll
  for (int r4 = 0; r4 < 4; ++r4) {
    const int row = r4 * 32 + srow;
    const int gsrc = sgs ^ (row & 7);
    async_load16(wbase + (size_t)row * 1024 + gsrc * 8, &Aw[row * 64 + sgs * 8]);
  }
  // stage S (fp32 -> bf16), XOR-swizzled; rows = d, cols = e
  {
    const int r = t >> 2;           // 0..63 (d row)
    const int g0 = (t & 3) * 2;
    const float* sp = S + (size_t)bh * 4096 + r * 64;
#pragma unroll
    for (int gg = 0; gg < 2; ++gg) {
      const int g = g0 + gg;
      const int gs = g ^ (r & 7);
      const float4 f0 = *(const float4*)(sp + gs * 8);
      const float4 f1 = *(const float4*)(sp + gs * 8 + 4);
      union { unsigned short u[8]; uint4 v; } pk;
      pk.u[0] = bf16_bits(f0.x); pk.u[1] = bf16_bits(f0.y);
      pk.u[2] = bf16_bits(f0.z); pk.u[3] = bf16_bits(f0.w);
      pk.u[4] = bf16_bits(f1.x); pk.u[5] = bf16_bits(f1.y);
      pk.u[6] = bf16_bits(f1.z); pk.u[7] = bf16_bits(f1.w);
      *(uint4*)&Sb[r * 64 + g * 8] = pk.v;
    }
  }
  __syncthreads();

  floatx4 acc[2][4];
#pragma unroll
  for (int i = 0; i < 2; ++i)
#pragma unroll
    for (int j = 0; j < 4; ++j)
      acc[i][j] = (floatx4){0.f, 0.f, 0.f, 0.f};

#pragma unroll
  for (int ks = 0; ks < 2; ++ks) {
    bf16x8 af[2], bfv[4];
#pragma unroll
    for (int i = 0; i < 2; ++i) {
      const int row = wave * 32 + i * 16 + (lane & 15);
      const int g = ks * 4 + (lane >> 4);
      af[i] = *(const bf16x8*)&Aw[row * 64 + (g ^ (row & 7)) * 8];
    }
#pragma unroll
    for (int j = 0; j < 4; ++j) {
      const int row = j * 16 + (lane & 15);       // d
      const int g = ks * 4 + (lane >> 4);
      bfv[j] = *(const bf16x8*)&Sb[row * 64 + (g ^ (row & 7)) * 8];
    }
#pragma unroll
    for (int i = 0; i < 2; ++i)
#pragma unroll
      for (int j = 0; j < 4; ++j)
        acc[i][j] = __builtin_amdgcn_mfma_f32_16x16x32_bf16(
            af[i], bfv[j], acc[i][j], 0, 0, 0);
  }

  const int ccol = lane & 15;
  const int crow = (lane >> 4) * 4;
  bf16_t* Wt = WeffT + (size_t)b * 1024 * 1024;
#pragma unroll
  for (int i = 0; i < 2; ++i) {
#pragma unroll
    for (int j = 0; j < 4; ++j) {
      const int hd = hh * 64 + j * 16 + ccol;
      const int n = nt * 128 + wave * 32 + i * 16 + crow;
#pragma unroll
      for (int r = 0; r < 4; ++r)
        Wt[(size_t)(n + r) * 1024 + hd] = __float2bfloat16(acc[i][j][r]);
    }
  }
}

// out[m][n] = sum_hd Q[m][hd] * WeffT[b][n][hd]. 16x16x32 MFMA, direct fp32 stores.
// BM=64 x BN=128 tiles -> grid (64,8) = 512 blocks = 2 blocks/CU.
__global__ __launch_bounds__(256, 2)
void gemm_final(const bf16_t* __restrict__ Q, const bf16_t* __restrict__ WeffT,
                float* __restrict__ C)
{
  __shared__ alignas(16) __bf16 As[64 * BK];    // Q tile
  __shared__ alignas(16) __bf16 Bs[128 * BK];   // WeffT tile

  const int t = threadIdx.x;
  const int lane = t & 63;
  const int wave = t >> 6;
  const int wm = wave >> 1;   // 0..1 (32-row strips)
  const int wn = wave & 1;    // 0..1 (64-col strips)

  const int m0 = blockIdx.x * 64;
  const int n0 = blockIdx.y * 128;
  const bf16_t* __restrict__ B = WeffT + (size_t)(m0 >> 11) * 1024 * 1024;

  floatx4 acc[2][4];
#pragma unroll
  for (int i = 0; i < 2; ++i)
#pragma unroll
    for (int j = 0; j < 4; ++j)
      acc[i][j] = (floatx4){0.f, 0.f, 0.f, 0.f};

  const int srow = t >> 3;
  const int sgs = t & 7;

  for (int k0 = 0; k0 < 1024; k0 += BK) {
#pragma unroll
    for (int r2 = 0; r2 < 2; ++r2) {
      const int row = r2 * 32 + srow;
      const int gsrc = sgs ^ (row & 7);
      async_load16(Q + (size_t)(m0 + row) * 1024 + k0 + gsrc * 8,
                   &As[row * BK + sgs * 8]);
    }
#pragma unroll
    for (int r4 = 0; r4 < 4; ++r4) {
      const int row = r4 * 32 + srow;
      const int gsrc = sgs ^ (row & 7);
      async_load16(B + (size_t)(n0 + row) * 1024 + k0 + gsrc * 8,
                   &Bs[row * BK + sgs * 8]);
    }
    __syncthreads();
#pragma unroll
    for (int ks = 0; ks < 2; ++ks) {
      bf16x8 af[2], bfv[4];
#pragma unroll
      for (int i = 0; i < 2; ++i) {
        const int row = wm * 32 + i * 16 + (lane & 15);
        const int g = ks * 4 + (lane >> 4);
        af[i] = *(const bf16x8*)&As[row * BK + (g ^ (row & 7)) * 8];
      }
#pragma unroll
      for (int j = 0; j < 4; ++j) {
        const int row = wn * 64 + j * 16 + (lane & 15);
        const int g = ks * 4 + (lane >> 4);
        bfv[j] = *(const bf16x8*)&Bs[row * BK + (g ^ (row & 7)) * 8];
      }
#pragma unroll
      for (int i = 0; i < 2; ++i)
#pragma unroll
        for (int j = 0; j < 4; ++j)
          acc[i][j] = __builtin_amdgcn_mfma_f32_16x16x32_bf16(
              af[i], bfv[j], acc[i][j], 0, 0, 0);
    }
    __syncthreads();
  }

  const int ccol = lane & 15;
  const int crow = (lane >> 4) * 4;
#pragma unroll
  for (int i = 0; i < 2; ++i) {
#pragma unroll
    for (int j = 0; j < 4; ++j) {
      const int gcol = n0 + wn * 64 + j * 16 + ccol;
      const int grow = m0 + wm * 32 + i * 16 + crow;
#pragma unroll
      for (int r = 0; r < 4; ++r)
        C[(size_t)(grow + r) * 1024 + gcol] = acc[i][j][r];
    }
  }
}

extern "C" void kernel_launch(void* const* d_in, const int* in_sizes, int n_in,
                              void* d_out, int out_size, void* d_ws, size_t ws_size,
                              hipStream_t stream)
{
  const float* h  = (const float*)d_in[0];
  const float* Wq = (const float*)d_in[1];
  const float* Wk = (const float*)d_in[2];
  const float* Wv = (const float*)d_in[3];
  // d_in[4] = Wspan: dead code in reference
  const float* Wo = (const float*)d_in[5];
  float* out = (float*)d_out;

  char* ws = (char*)d_ws;
  bf16_t* hb    = (bf16_t*)(ws);                 // [4096,1024] bf16, 8 MB (dead after QKV)
  bf16_t* WeffT = (bf16_t*)(ws);                 // [2][1024,1024] bf16, 4 MB (reuses hb)
  bf16_t* Wqb   = (bf16_t*)(ws + (8u << 20));    // 2 MB each
  bf16_t* Wkb   = (bf16_t*)(ws + (10u << 20));
  bf16_t* Wvb   = (bf16_t*)(ws + (12u << 20));
  bf16_t* Wob   = (bf16_t*)(ws + (14u << 20));
  bf16_t* Qbuf  = (bf16_t*)(ws + (16u << 20));   // [4096,1024] bf16, 8 MB
  bf16_t* Kt    = (bf16_t*)(ws + (24u << 20));   // [32][64][2048] bf16, 8 MB
  bf16_t* Vt    = (bf16_t*)(ws + (32u << 20));   // [32][64][2048] bf16, 8 MB
  float*  S     = (float*) (ws + (40u << 20));   // [32][64][64] fp32, d-major

  // conversions + S zero (one launch)
  cvt_all<<<dim3(8194), 256, 0, stream>>>(h, Wq, Wk, Wv, Wo, hb, Wqb, Wkb, Wvb, Wob, S);

  // Q -> Qbuf; K,V -> Kt,Vt (transposed, m-contiguous). 256x256 tiles, ring schedule.
  gemm_qkv<<<dim3(16, 12), 512, 0, stream>>>(hb, Wqb, Wkb, Wvb, Qbuf, Kt, Vt);
  // S[bh][d][e] = sum_m K*V (MFMA NT, split-K=8, atomic fp32 on tiny S)
  ktv_gemm<<<dim3(32, 8), 256, 0, stream>>>(Kt, Vt, S);
  // W_effT[b][n][hd] = sum_e Wo[n][he] * S[bh][d][e]  (overwrites dead hb)
  weff_mfma<<<dim3(32, 8), 256, 0, stream>>>(Wob, S, WeffT);
  // out = Q @ W_effT^T, direct fp32 stores, 2 blocks/CU
  gemm_final<<<dim3(64, 8), 256, 0, stream>>>(Qbuf, WeffT, out);
}